// Round 1
// baseline (668.264 us; speedup 1.0000x reference)
//
#include <hip/hip_runtime.h>
#include <hip/hip_bf16.h>

#define HEADS 4
#define DH    128
#define CIN   256
#define NPIX  16384
#define NB    4
#define HID   512   // HEADS*DH

__device__ inline float bf2f(unsigned short u) {
    return __uint_as_float(((unsigned)u) << 16);
}

// ---------------------------------------------------------------------------
// K1: kv GEMM.  C[b,m,n] = sum_c w_qkv[512+m,c] * x[b,c,n],  m in [0,1024)
//     m <  512 -> k logits (row b*512+m), m >= 512 -> v (row b*512+m-512)
//     output stored bf16.
// grid (NPIX/128, 1024/128, NB), block 256
// ---------------------------------------------------------------------------
__global__ __launch_bounds__(256) void kv_gemm(const float* __restrict__ x,
                                               const float* __restrict__ w_qkv,
                                               __hip_bfloat16* __restrict__ kbuf,
                                               __hip_bfloat16* __restrict__ vbuf)
{
    const int n0 = blockIdx.x * 128;
    const int m0 = blockIdx.y * 128;
    const int b  = blockIdx.z;
    const int t  = threadIdx.x;
    const int tx = t & 15, ty = t >> 4;

    __shared__ float At[16][136];   // [kk][m]  (transposed W tile)
    __shared__ float Bt[16][136];   // [kk][n]  (x tile)

    float acc[8][8] = {};
    const float* xb = x + (size_t)b * CIN * NPIX;

    for (int c0 = 0; c0 < CIN; c0 += 16) {
        // load W tile: 128 rows x 16 c, transposed into At[kk][row]
        {
            const int row = t >> 1;
            const int cc0 = (t & 1) * 8;
            const float* src = w_qkv + (size_t)(512 + m0 + row) * CIN + c0 + cc0;
#pragma unroll
            for (int i = 0; i < 8; ++i) At[cc0 + i][row] = src[i];
        }
        // load x tile: 16 rows (c) x 128 cols (n)
        {
            const int r    = t >> 4;
            const int col0 = (t & 15) * 8;
            const float* src = xb + (size_t)(c0 + r) * NPIX + n0 + col0;
#pragma unroll
            for (int i = 0; i < 8; ++i) Bt[r][col0 + i] = src[i];
        }
        __syncthreads();
#pragma unroll
        for (int kk = 0; kk < 16; ++kk) {
            float a[8], bb[8];
#pragma unroll
            for (int i = 0; i < 8; ++i) a[i] = At[kk][ty * 8 + i];
#pragma unroll
            for (int j = 0; j < 8; ++j) bb[j] = Bt[kk][tx * 8 + j];
#pragma unroll
            for (int i = 0; i < 8; ++i)
#pragma unroll
                for (int j = 0; j < 8; ++j)
                    acc[i][j] += a[i] * bb[j];
        }
        __syncthreads();
    }

#pragma unroll
    for (int i = 0; i < 8; ++i) {
        const int m = m0 + ty * 8 + i;
        __hip_bfloat16* dst = (m < 512)
            ? kbuf + ((size_t)b * 512 + m) * NPIX
            : vbuf + ((size_t)b * 512 + (m - 512)) * NPIX;
#pragma unroll
        for (int j = 0; j < 8; ++j)
            dst[n0 + tx * 8 + j] = __float2bfloat16(acc[i][j]);
    }
}

// ---------------------------------------------------------------------------
// K2: per-row softmax stats over n for k.  2048 rows, 1 block/row.
// ---------------------------------------------------------------------------
__global__ __launch_bounds__(256) void rowstats(const __hip_bfloat16* __restrict__ kbuf,
                                                float* __restrict__ rmax,
                                                float* __restrict__ rinv)
{
    const int row = blockIdx.x;
    const int t   = threadIdx.x;
    const ushort4* k4 = reinterpret_cast<const ushort4*>(kbuf + (size_t)row * NPIX);

    float m = -1e30f;
    for (int i = t; i < NPIX / 4; i += 256) {
        ushort4 u = k4[i];
        m = fmaxf(m, bf2f(u.x)); m = fmaxf(m, bf2f(u.y));
        m = fmaxf(m, bf2f(u.z)); m = fmaxf(m, bf2f(u.w));
    }
#pragma unroll
    for (int off = 32; off; off >>= 1) m = fmaxf(m, __shfl_xor(m, off));
    __shared__ float sm[4];
    if ((t & 63) == 0) sm[t >> 6] = m;
    __syncthreads();
    m = fmaxf(fmaxf(sm[0], sm[1]), fmaxf(sm[2], sm[3]));

    float s = 0.f;
    for (int i = t; i < NPIX / 4; i += 256) {
        ushort4 u = k4[i];
        s += __expf(bf2f(u.x) - m) + __expf(bf2f(u.y) - m)
           + __expf(bf2f(u.z) - m) + __expf(bf2f(u.w) - m);
    }
#pragma unroll
    for (int off = 32; off; off >>= 1) s += __shfl_xor(s, off);
    __shared__ float ss[4];
    if ((t & 63) == 0) ss[t >> 6] = s;
    __syncthreads();
    if (t == 0) {
        rmax[row] = m;
        rinv[row] = 1.0f / (ss[0] + ss[1] + ss[2] + ss[3]);
    }
}

// ---------------------------------------------------------------------------
// K3: ctx partials.  partial[bh,chunk,d,e] = sum_{n in chunk} p[d,n]*v[e,n]
//     p = exp(k-max)*rinv computed on the fly.  chunk = 512 n.
// grid (32, 16), block 256
// ---------------------------------------------------------------------------
__global__ __launch_bounds__(256) void ctx_partial(const __hip_bfloat16* __restrict__ kbuf,
                                                   const __hip_bfloat16* __restrict__ vbuf,
                                                   const float* __restrict__ rmax,
                                                   const float* __restrict__ rinv,
                                                   float* __restrict__ partial)
{
    const int chunk = blockIdx.x, bh = blockIdx.y;
    const int n_base = chunk * 512;
    const int t = threadIdx.x;
    const int tx = t & 15, ty = t >> 4;

    __shared__ float Pt[16][136];   // [nn][d]
    __shared__ float Vt[16][136];   // [nn][e]

    float acc[8][8] = {};
    const __hip_bfloat16* kb = kbuf + (size_t)bh * DH * NPIX;
    const __hip_bfloat16* vb = vbuf + (size_t)bh * DH * NPIX;
    const float* rm = rmax + bh * DH;
    const float* ri = rinv + bh * DH;

    for (int nn0 = 0; nn0 < 512; nn0 += 16) {
        {
            const int d  = t >> 1;
            const int c0 = (t & 1) * 8;
            const unsigned short* src =
                reinterpret_cast<const unsigned short*>(kb + (size_t)d * NPIX + n_base + nn0 + c0);
            const float m = rm[d], r = ri[d];
#pragma unroll
            for (int i = 0; i < 8; ++i)
                Pt[c0 + i][d] = __expf(bf2f(src[i]) - m) * r;
        }
        {
            const int e  = t >> 1;
            const int c0 = (t & 1) * 8;
            const unsigned short* src =
                reinterpret_cast<const unsigned short*>(vb + (size_t)e * NPIX + n_base + nn0 + c0);
#pragma unroll
            for (int i = 0; i < 8; ++i)
                Vt[c0 + i][e] = bf2f(src[i]);
        }
        __syncthreads();
#pragma unroll
        for (int kk = 0; kk < 16; ++kk) {
            float a[8], bb[8];
#pragma unroll
            for (int i = 0; i < 8; ++i) a[i] = Pt[kk][ty * 8 + i];
#pragma unroll
            for (int j = 0; j < 8; ++j) bb[j] = Vt[kk][tx * 8 + j];
#pragma unroll
            for (int i = 0; i < 8; ++i)
#pragma unroll
                for (int j = 0; j < 8; ++j)
                    acc[i][j] += a[i] * bb[j];
        }
        __syncthreads();
    }

    float* dst = partial + ((size_t)bh * 32 + chunk) * (DH * DH);
#pragma unroll
    for (int i = 0; i < 8; ++i)
#pragma unroll
        for (int j = 0; j < 8; ++j)
            dst[(ty * 8 + i) * DH + tx * 8 + j] = acc[i][j];
}

// ---------------------------------------------------------------------------
// K4: reduce ctx partials over 32 chunks.
// ---------------------------------------------------------------------------
__global__ __launch_bounds__(256) void ctx_reduce(const float* __restrict__ partial,
                                                  float* __restrict__ ctx)
{
    const int idx = blockIdx.x * 256 + threadIdx.x;   // 16*16384
    const int bh = idx / (DH * DH), de = idx % (DH * DH);
    float s = 0.f;
    for (int c = 0; c < 32; ++c)
        s += partial[((size_t)bh * 32 + c) * (DH * DH) + de];
    ctx[idx] = s;
}

// ---------------------------------------------------------------------------
// K5: Abar[b, h*128+e, c] = sum_d ctx[b,h,d,e] * w_q[h*128+d, c]
// grid (512, 4), block 256 (threads over c)
// ---------------------------------------------------------------------------
__global__ __launch_bounds__(256) void abar_kernel(const float* __restrict__ ctx,
                                                   const float* __restrict__ w_qkv,
                                                   float* __restrict__ Abar)
{
    const int m = blockIdx.x, b = blockIdx.y;
    const int h = m >> 7, e = m & 127;
    const int c = threadIdx.x;
    const float* cx = ctx + (size_t)(b * HEADS + h) * (DH * DH);
    float s = 0.f;
    for (int d = 0; d < DH; ++d)
        s += cx[d * DH + e] * w_qkv[(size_t)(h * DH + d) * CIN + c];
    Abar[((size_t)b * HID + m) * CIN + c] = s;
}

// ---------------------------------------------------------------------------
// K6: F[b,o,c] = sum_m w_out[o,m] * Abar[b,m,c]
// grid (256, 4), block 256 (threads over c)
// ---------------------------------------------------------------------------
__global__ __launch_bounds__(256) void f_kernel(const float* __restrict__ Abar,
                                                const float* __restrict__ w_out,
                                                float* __restrict__ F)
{
    const int o = blockIdx.x, b = blockIdx.y;
    const int c = threadIdx.x;
    const float* ab = Abar + (size_t)b * HID * CIN + c;
    const float* wo = w_out + (size_t)o * HID;
    float s = 0.f;
    for (int m = 0; m < HID; ++m) s += wo[m] * ab[(size_t)m * CIN];
    F[((size_t)b * CIN + o) * CIN + c] = s;
}

// ---------------------------------------------------------------------------
// K7: final[b,o,n] = sum_c F[b,o,c]*x[b,c,n] + b_out[o]
// grid (NPIX/128, 256/128, NB), block 256
// ---------------------------------------------------------------------------
__global__ __launch_bounds__(256) void out_gemm(const float* __restrict__ x,
                                                const float* __restrict__ F,
                                                const float* __restrict__ b_out,
                                                float* __restrict__ out)
{
    const int n0 = blockIdx.x * 128;
    const int m0 = blockIdx.y * 128;
    const int b  = blockIdx.z;
    const int t  = threadIdx.x;
    const int tx = t & 15, ty = t >> 4;

    __shared__ float At[16][136];
    __shared__ float Bt[16][136];

    float acc[8][8] = {};
    const float* xb = x + (size_t)b * CIN * NPIX;
    const float* Fb = F + (size_t)b * CIN * CIN;

    for (int c0 = 0; c0 < CIN; c0 += 16) {
        {
            const int row = t >> 1;
            const int cc0 = (t & 1) * 8;
            const float* src = Fb + (size_t)(m0 + row) * CIN + c0 + cc0;
#pragma unroll
            for (int i = 0; i < 8; ++i) At[cc0 + i][row] = src[i];
        }
        {
            const int r    = t >> 4;
            const int col0 = (t & 15) * 8;
            const float* src = xb + (size_t)(c0 + r) * NPIX + n0 + col0;
#pragma unroll
            for (int i = 0; i < 8; ++i) Bt[r][col0 + i] = src[i];
        }
        __syncthreads();
#pragma unroll
        for (int kk = 0; kk < 16; ++kk) {
            float a[8], bb[8];
#pragma unroll
            for (int i = 0; i < 8; ++i) a[i] = At[kk][ty * 8 + i];
#pragma unroll
            for (int j = 0; j < 8; ++j) bb[j] = Bt[kk][tx * 8 + j];
#pragma unroll
            for (int i = 0; i < 8; ++i)
#pragma unroll
                for (int j = 0; j < 8; ++j)
                    acc[i][j] += a[i] * bb[j];
        }
        __syncthreads();
    }

#pragma unroll
    for (int i = 0; i < 8; ++i) {
        const int o = m0 + ty * 8 + i;
        const float bias = b_out[o];
        float* dst = out + ((size_t)b * CIN + o) * NPIX + n0 + tx * 8;
#pragma unroll
        for (int j = 0; j < 8; ++j) dst[j] = acc[i][j] + bias;
    }
}

// ---------------------------------------------------------------------------
extern "C" void kernel_launch(void* const* d_in, const int* in_sizes, int n_in,
                              void* d_out, int out_size, void* d_ws, size_t ws_size,
                              hipStream_t stream)
{
    const float* x     = (const float*)d_in[0];
    const float* w_qkv = (const float*)d_in[1];
    const float* w_out = (const float*)d_in[2];
    const float* b_out = (const float*)d_in[3];
    float* out = (float*)d_out;

    char* ws = (char*)d_ws;
    __hip_bfloat16* kbuf = (__hip_bfloat16*)ws;                       // 64 MB
    __hip_bfloat16* vbuf = (__hip_bfloat16*)(ws + (64ull << 20));     // 64 MB
    float* rmax    = (float*)(ws + (128ull << 20));                   // 8 KB
    float* rinv    = rmax + 2048;                                     // 8 KB
    float* ctx     = rinv + 2048;                                     // 1 MB
    float* Abar    = ctx + 16 * DH * DH;                              // 2 MB
    float* F       = Abar + (size_t)NB * HID * CIN;                   // 1 MB
    float* partial = F + (size_t)NB * CIN * CIN;                      // 32 MB

    kv_gemm<<<dim3(NPIX / 128, 1024 / 128, NB), 256, 0, stream>>>(x, w_qkv, kbuf, vbuf);
    rowstats<<<2048, 256, 0, stream>>>(kbuf, rmax, rinv);
    ctx_partial<<<dim3(32, 16), 256, 0, stream>>>(kbuf, vbuf, rmax, rinv, partial);
    ctx_reduce<<<(16 * DH * DH) / 256, 256, 0, stream>>>(partial, ctx);
    abar_kernel<<<dim3(512, NB), 256, 0, stream>>>(ctx, w_qkv, Abar);
    f_kernel<<<dim3(256, NB), 256, 0, stream>>>(Abar, w_out, F);
    out_gemm<<<dim3(NPIX / 128, CIN / 128, NB), 256, 0, stream>>>(x, F, b_out, out);
}

// Round 2
// 221.825 us; speedup vs baseline: 3.0126x; 3.0126x over previous
//
#include <hip/hip_runtime.h>
#include <hip/hip_bf16.h>

#define HEADS 4
#define DH    128
#define CIN   256
#define NPIX  16384
#define NB    4
#define HID   512

typedef __attribute__((ext_vector_type(8))) short bf16x8;   // 8 bf16 = 4 VGPR
typedef __attribute__((ext_vector_type(4))) float f32x4;

__device__ __forceinline__ float bf2f(unsigned short u) {
    return __uint_as_float(((unsigned)u) << 16);
}
__device__ __forceinline__ unsigned short f2bfu(float f) {
    union { __hip_bfloat16 h; unsigned short u; } cv;
    cv.h = __float2bfloat16(f);
    return cv.u;
}
__device__ __forceinline__ unsigned expack(unsigned w) {
    float lo = __expf(bf2f((unsigned short)(w & 0xffffu)));
    float hi = __expf(bf2f((unsigned short)(w >> 16)));
    return (unsigned)f2bfu(lo) | ((unsigned)f2bfu(hi) << 16);
}

// LDS tile: 128 rows x 64 bf16 (128B/row).  XOR swizzle: 16B slot s of row r
// lives at physical slot s ^ (r&7)  ->  fragment reads are conflict-free.
__device__ __forceinline__ int swz(int row, int usoff) {   // usoff: ushort units 0..63
    return row * 64 + (usoff ^ ((row & 7) << 3));
}

// stage one 128x64 bf16 tile (row-major, K-contiguous source) into swizzled LDS
template<bool EXP>
__device__ __forceinline__ void stage_tile(const unsigned short* __restrict__ g,
                                           size_t ldk, unsigned short* s, int t)
{
#pragma unroll
    for (int p = 0; p < 4; ++p) {
        const int row  = p * 32 + (t >> 3);
        const int slot = t & 7;
        uint4 u = *reinterpret_cast<const uint4*>(g + (size_t)row * ldk + slot * 8);
        if (EXP) {
            u.x = expack(u.x); u.y = expack(u.y);
            u.z = expack(u.z); u.w = expack(u.w);
        }
        *reinterpret_cast<uint4*>(&s[swz(row, slot * 8)]) = u;
    }
}

// 4 waves, wave (wr,wc) owns a 64x64 quadrant = 4x4 fragments of 16x16.
__device__ __forceinline__ void mfma_tile(const unsigned short* sA,
                                          const unsigned short* sB,
                                          f32x4 (&acc)[4][4], int t)
{
    const int lane = t & 63, wid = t >> 6;
    const int wr = (wid >> 1) * 64, wc = (wid & 1) * 64;
    const int lrow = lane & 15, lk = (lane >> 4) * 8;
#pragma unroll
    for (int ks = 0; ks < 2; ++ks) {
        bf16x8 a[4], b[4];
#pragma unroll
        for (int f = 0; f < 4; ++f) {
            const int ar = wr + f * 16 + lrow;
            a[f] = *reinterpret_cast<const bf16x8*>(&sA[swz(ar, ks * 32 + lk)]);
            const int br = wc + f * 16 + lrow;
            b[f] = *reinterpret_cast<const bf16x8*>(&sB[swz(br, ks * 32 + lk)]);
        }
#pragma unroll
        for (int fi = 0; fi < 4; ++fi)
#pragma unroll
            for (int fj = 0; fj < 4; ++fj)
                acc[fi][fj] = __builtin_amdgcn_mfma_f32_16x16x32_bf16(
                    a[fi], b[fj], acc[fi][fj], 0, 0, 0);
    }
}

// ---------------------------------------------------------------------------
// K0a: x[b][c][n] fp32 -> xt[b][n][c] bf16   (transpose via LDS)
// grid (256, 4, 4), block 256
// ---------------------------------------------------------------------------
__global__ __launch_bounds__(256) void xt_convert(const float* __restrict__ x,
                                                  unsigned short* __restrict__ xt)
{
    __shared__ float tile[64][65];
    const int b = blockIdx.z, c0 = blockIdx.y * 64, n0 = blockIdx.x * 64;
    const int t = threadIdx.x;
    const int tn = t & 63, tg = t >> 6;
    const float* xb = x + ((size_t)b * CIN + c0) * NPIX + n0;
#pragma unroll
    for (int r = 0; r < 16; ++r) {
        const int c = tg * 16 + r;
        tile[c][tn] = xb[(size_t)c * NPIX + tn];
    }
    __syncthreads();
    unsigned short* dst = xt + ((size_t)b * NPIX + n0) * CIN + c0;
#pragma unroll
    for (int r = 0; r < 16; ++r) {
        const int n = tg * 16 + r;
        dst[(size_t)n * CIN + tn] = f2bfu(tile[tn][n]);
    }
}

// K0b: w_qkv fp32 -> bf16 (all 1536 rows; kv uses rows 512..1536)
__global__ __launch_bounds__(256) void wconv(const float* __restrict__ w,
                                             unsigned short* __restrict__ wbf)
{
    const int i = blockIdx.x * 256 + threadIdx.x;
    wbf[i] = f2bfu(w[i]);
}

// ---------------------------------------------------------------------------
// K1: kv GEMM (MFMA).  C[m,n] = sum_c W[512+m,c] * xt[n,c]
// grid (128, 8, 4), block 256
// ---------------------------------------------------------------------------
__global__ __launch_bounds__(256) void kv_gemm_mfma(const unsigned short* __restrict__ xt,
                                                    const unsigned short* __restrict__ wbf,
                                                    __hip_bfloat16* __restrict__ kbuf,
                                                    __hip_bfloat16* __restrict__ vbuf)
{
    __shared__ unsigned short sA[128 * 64], sB[128 * 64];
    const int t  = threadIdx.x;
    const int n0 = blockIdx.x * 128;
    const int m0 = blockIdx.y * 128;
    const int b  = blockIdx.z;
    const unsigned short* gA = wbf + (size_t)(512 + m0) * CIN;
    const unsigned short* gB = xt + ((size_t)b * NPIX + n0) * CIN;

    f32x4 acc[4][4] = {};
    for (int k0 = 0; k0 < CIN; k0 += 64) {
        stage_tile<false>(gA + k0, CIN, sA, t);
        stage_tile<false>(gB + k0, CIN, sB, t);
        __syncthreads();
        mfma_tile(sA, sB, acc, t);
        __syncthreads();
    }

    const int lane = t & 63, wid = t >> 6;
    const int wr = (wid >> 1) * 64, wc = (wid & 1) * 64;
    const int col = lane & 15, r0 = (lane >> 4) * 4;
    const bool isK = (m0 < 512);
    __hip_bfloat16* base = isK ? kbuf : vbuf;
    const int mb = isK ? m0 : m0 - 512;
#pragma unroll
    for (int fi = 0; fi < 4; ++fi)
#pragma unroll
        for (int fj = 0; fj < 4; ++fj)
#pragma unroll
            for (int r = 0; r < 4; ++r) {
                const int m = mb + wr + fi * 16 + r0 + r;
                const int n = n0 + wc + fj * 16 + col;
                base[((size_t)b * 512 + m) * NPIX + n] = __float2bfloat16(acc[fi][fj][r]);
            }
}

// ---------------------------------------------------------------------------
// K2: S[row] = sum_n exp(k[row,n])   (no max subtraction: logits are O(1))
// grid 2048, block 256
// ---------------------------------------------------------------------------
__global__ __launch_bounds__(256) void rowsum(const unsigned short* __restrict__ kbuf,
                                              float* __restrict__ S)
{
    const int row = blockIdx.x;
    const int t   = threadIdx.x;
    const uint4* k4 = reinterpret_cast<const uint4*>(kbuf + (size_t)row * NPIX);
    float s = 0.f;
    for (int i = t; i < NPIX / 8; i += 256) {
        uint4 u = k4[i];
        s += __expf(bf2f((unsigned short)(u.x & 0xffffu))) + __expf(bf2f((unsigned short)(u.x >> 16)))
           + __expf(bf2f((unsigned short)(u.y & 0xffffu))) + __expf(bf2f((unsigned short)(u.y >> 16)))
           + __expf(bf2f((unsigned short)(u.z & 0xffffu))) + __expf(bf2f((unsigned short)(u.z >> 16)))
           + __expf(bf2f((unsigned short)(u.w & 0xffffu))) + __expf(bf2f((unsigned short)(u.w >> 16)));
    }
#pragma unroll
    for (int off = 32; off; off >>= 1) s += __shfl_xor(s, off);
    __shared__ float ss[4];
    if ((t & 63) == 0) ss[t >> 6] = s;
    __syncthreads();
    if (t == 0) S[row] = ss[0] + ss[1] + ss[2] + ss[3];
}

// ---------------------------------------------------------------------------
// K3: ctx partials (MFMA).  partial[ksp,bh,d,e] = sum_{n in split} exp(k[d,n])*v[e,n]
// grid (16 ksp, 16 bh), block 256.  exp applied during LDS staging.
// ---------------------------------------------------------------------------
__global__ __launch_bounds__(256) void ctx_mfma(const unsigned short* __restrict__ kbuf,
                                                const unsigned short* __restrict__ vbuf,
                                                float* __restrict__ partial)
{
    __shared__ unsigned short sA[128 * 64], sB[128 * 64];
    const int t   = threadIdx.x;
    const int ksp = blockIdx.x;
    const int bh  = blockIdx.y;
    const unsigned short* gA = kbuf + (size_t)bh * 128 * NPIX + ksp * 1024;
    const unsigned short* gB = vbuf + (size_t)bh * 128 * NPIX + ksp * 1024;

    f32x4 acc[4][4] = {};
    for (int k0 = 0; k0 < 1024; k0 += 64) {
        stage_tile<true >(gA + k0, NPIX, sA, t);
        stage_tile<false>(gB + k0, NPIX, sB, t);
        __syncthreads();
        mfma_tile(sA, sB, acc, t);
        __syncthreads();
    }

    float* dst = partial + ((size_t)ksp * 16 + bh) * (128 * 128);
    const int lane = t & 63, wid = t >> 6;
    const int wr = (wid >> 1) * 64, wc = (wid & 1) * 64;
    const int col = lane & 15, r0 = (lane >> 4) * 4;
#pragma unroll
    for (int fi = 0; fi < 4; ++fi)
#pragma unroll
        for (int fj = 0; fj < 4; ++fj)
#pragma unroll
            for (int r = 0; r < 4; ++r)
                dst[(wr + fi * 16 + r0 + r) * 128 + wc + fj * 16 + col] = acc[fi][fj][r];
}

// K4: ctx_s[bh,d,e] = (1/S[bh*128+d]) * sum_ksp partial[ksp,bh,d,e]
__global__ __launch_bounds__(256) void ctx_reduce(const float* __restrict__ partial,
                                                  const float* __restrict__ S,
                                                  float* __restrict__ ctx_s)
{
    const int idx = blockIdx.x * 256 + threadIdx.x;   // 16 * 16384
    const int bh = idx >> 14, de = idx & 16383;
    const int d  = de >> 7;
    float s = 0.f;
#pragma unroll
    for (int k = 0; k < 16; ++k)
        s += partial[((size_t)k * 16 + bh) * 16384 + de];
    ctx_s[idx] = s * (1.0f / S[bh * 128 + d]);
}

// K5: Abar[b, h*128+e, c] = sum_d ctx_s[bh,d,e] * w_q[h*128+d, c]
__global__ __launch_bounds__(256) void abar_kernel(const float* __restrict__ ctx_s,
                                                   const float* __restrict__ w_qkv,
                                                   float* __restrict__ Abar)
{
    const int m = blockIdx.x, b = blockIdx.y;
    const int h = m >> 7, e = m & 127;
    const int c = threadIdx.x;
    const float* cx = ctx_s + (size_t)(b * HEADS + h) * (DH * DH);
    float s = 0.f;
    for (int d = 0; d < DH; ++d)
        s += cx[d * DH + e] * w_qkv[(size_t)(h * DH + d) * CIN + c];
    Abar[((size_t)b * HID + m) * CIN + c] = s;
}

// K6: fbf[b,o,c] = bf16( sum_m w_out[o,m] * Abar[b,m,c] )
__global__ __launch_bounds__(256) void f_kernel(const float* __restrict__ Abar,
                                                const float* __restrict__ w_out,
                                                unsigned short* __restrict__ fbf)
{
    const int o = blockIdx.x, b = blockIdx.y;
    const int c = threadIdx.x;
    const float* ab = Abar + (size_t)b * HID * CIN + c;
    const float* wo = w_out + (size_t)o * HID;
    float s = 0.f;
    for (int m = 0; m < HID; ++m) s += wo[m] * ab[(size_t)m * CIN];
    fbf[((size_t)b * CIN + o) * CIN + c] = f2bfu(s);
}

// ---------------------------------------------------------------------------
// K7: out GEMM (MFMA). out[b,o,n] = sum_c fbf[o,c]*xt[n,c] + b_out[o]
// grid (128, 2, 4), block 256
// ---------------------------------------------------------------------------
__global__ __launch_bounds__(256) void out_gemm_mfma(const unsigned short* __restrict__ xt,
                                                     const unsigned short* __restrict__ fbf,
                                                     const float* __restrict__ b_out,
                                                     float* __restrict__ out)
{
    __shared__ unsigned short sA[128 * 64], sB[128 * 64];
    const int t  = threadIdx.x;
    const int n0 = blockIdx.x * 128;
    const int m0 = blockIdx.y * 128;
    const int b  = blockIdx.z;
    const unsigned short* gA = fbf + ((size_t)b * CIN + m0) * CIN;
    const unsigned short* gB = xt + ((size_t)b * NPIX + n0) * CIN;

    f32x4 acc[4][4] = {};
    for (int k0 = 0; k0 < CIN; k0 += 64) {
        stage_tile<false>(gA + k0, CIN, sA, t);
        stage_tile<false>(gB + k0, CIN, sB, t);
        __syncthreads();
        mfma_tile(sA, sB, acc, t);
        __syncthreads();
    }

    const int lane = t & 63, wid = t >> 6;
    const int wr = (wid >> 1) * 64, wc = (wid & 1) * 64;
    const int col = lane & 15, r0 = (lane >> 4) * 4;
#pragma unroll
    for (int fi = 0; fi < 4; ++fi)
#pragma unroll
        for (int r = 0; r < 4; ++r) {
            const int o = m0 + wr + fi * 16 + r0 + r;
            const float bias = b_out[o];
#pragma unroll
            for (int fj = 0; fj < 4; ++fj) {
                const int n = n0 + wc + fj * 16 + col;
                out[((size_t)b * CIN + o) * NPIX + n] = acc[fi][fj][r] + bias;
            }
        }
}

// ---------------------------------------------------------------------------
extern "C" void kernel_launch(void* const* d_in, const int* in_sizes, int n_in,
                              void* d_out, int out_size, void* d_ws, size_t ws_size,
                              hipStream_t stream)
{
    const float* x     = (const float*)d_in[0];
    const float* w_qkv = (const float*)d_in[1];
    const float* w_out = (const float*)d_in[2];
    const float* b_out = (const float*)d_in[3];
    float* out = (float*)d_out;

    char* ws = (char*)d_ws;
    // layout (bytes):
    unsigned short* xt   = (unsigned short*)ws;                          // 32 MB
    unsigned short* kbuf = (unsigned short*)(ws + (32ull  << 20));       // 64 MB (dead after ctx)
    unsigned short* vbuf = (unsigned short*)(ws + (96ull  << 20));       // 64 MB (dead after ctx)
    unsigned short* wbf  = (unsigned short*)(ws + (160ull << 20));       // 768 KB (dead after kv)
    float*          S    = (float*)(ws + (161ull << 20));                // 8 KB
    // reuse of dead regions:
    float*          ctx_s = (float*)(ws + (32ull << 20));                // 1 MB  @ kbuf
    float*          Abar  = (float*)(ws + (33ull << 20));                // 2 MB  @ kbuf+1MB
    unsigned short* fbf   = (unsigned short*)(ws + (160ull << 20));      // 512 KB @ wbf
    // ctx partials live in d_out (16 MB of 64 MB), overwritten by out_gemm
    float* partial = (float*)d_out;

    xt_convert<<<dim3(NPIX / 64, CIN / 64, NB), 256, 0, stream>>>(x, xt);
    wconv<<<(1536 * 256) / 256, 256, 0, stream>>>(w_qkv, wbf);
    kv_gemm_mfma<<<dim3(NPIX / 128, 1024 / 128, NB), 256, 0, stream>>>(
        xt, wbf, (__hip_bfloat16*)kbuf, (__hip_bfloat16*)vbuf);
    rowsum<<<2048, 256, 0, stream>>>(kbuf, S);
    ctx_mfma<<<dim3(16, 16), 256, 0, stream>>>(kbuf, vbuf, partial);
    ctx_reduce<<<(16 * 16384) / 256, 256, 0, stream>>>(partial, S, ctx_s);
    abar_kernel<<<dim3(512, NB), 256, 0, stream>>>(ctx_s, w_qkv, Abar);
    f_kernel<<<dim3(256, NB), 256, 0, stream>>>(Abar, w_out, fbf);
    out_gemm_mfma<<<dim3(NPIX / 128, CIN / 128, NB), 256, 0, stream>>>(xt, fbf, b_out, out);
}